// Round 2
// baseline (118.756 us; speedup 1.0000x reference)
//
#include <hip/hip_runtime.h>

namespace {

constexpr int HIMG = 512;
constexpr int WIMG = 512;
constexpr int CH   = 3;
constexpr int ROWF = WIMG * CH;            // 1536 floats per image row
constexpr int NT   = 384;                  // one float4 column per thread (384*4 = 1536)
constexpr int RCH  = 8;                    // rows staged per iteration
constexpr int HCHUNK = 32;                 // output rows per block
constexpr int NITER  = HCHUNK / RCH;       // 4
constexpr int HALO = 12;                   // LDS halo floats each side (>= 9, float4-aligned)
constexpr int LROW = HALO + ROWF + HALO;   // 1560 floats per LDS row
constexpr int NGRP = ROWF / 8;             // 192 eight-float output groups per row

// exp(-x^2/(2*1.5^2)), double precision (matches cv2.getGaussianKernel)
constexpr double KD0 = 0.13533528323661270;  // x=3
constexpr double KD1 = 0.41111229050718745;  // x=2
constexpr double KD2 = 0.80073740291680804;  // x=1
constexpr double KSUM = 1.0 + 2.0 * (KD0 + KD1 + KD2);

__global__ __launch_bounds__(NT) void gauss7(const float* __restrict__ in,
                                             float* __restrict__ out) {
  constexpr float W[7] = {
      (float)(KD0 / KSUM), (float)(KD1 / KSUM), (float)(KD2 / KSUM),
      (float)(1.0 / KSUM),
      (float)(KD2 / KSUM), (float)(KD1 / KSUM), (float)(KD0 / KSUM)};

  __shared__ __align__(16) float lds[RCH][LROW];

  const int b  = blockIdx.x;
  const int n  = b >> 4;       // 16 H-chunks per image
  const int hc = b & 15;
  const int h0 = hc * HCHUNK;
  const int t  = threadIdx.x;

  const float* inN  = in  + (size_t)n * HIMG * ROWF;
  float*       outN = out + (size_t)n * HIMG * ROWF;

  // ---- vertical rolling window: win[0..5] = rows [h-3 .. h+2] (float4 col t) ----
  float4 win[6];
#pragma unroll
  for (int i = 0; i < 6; ++i) {
    int r  = h0 - 3 + i;
    int rr = r < 0 ? -r : r;                       // top reflect-101 (preload only)
    win[i] = reinterpret_cast<const float4*>(inN + (size_t)rr * ROWF)[t];
  }

  for (int it = 0; it < NITER; ++it) {
    const int hbase = h0 + it * RCH;

    // ---- stage RCH vertically-blurred rows into LDS ----
    float4 nw[RCH];
#pragma unroll
    for (int i = 0; i < RCH; ++i) {                // 8 dwordx4 loads in flight
      int r  = hbase + 3 + i;                      // r >= 3 always
      int rr = r > HIMG - 1 ? 2 * (HIMG - 1) - r : r;
      nw[i]  = reinterpret_cast<const float4*>(inN + (size_t)rr * ROWF)[t];
    }
#pragma unroll
    for (int i = 0; i < RCH; ++i) {
      float4 v;
      v.x = W[0]*win[0].x + W[1]*win[1].x + W[2]*win[2].x + W[3]*win[3].x +
            W[4]*win[4].x + W[5]*win[5].x + W[6]*nw[i].x;
      v.y = W[0]*win[0].y + W[1]*win[1].y + W[2]*win[2].y + W[3]*win[3].y +
            W[4]*win[4].y + W[5]*win[5].y + W[6]*nw[i].y;
      v.z = W[0]*win[0].z + W[1]*win[1].z + W[2]*win[2].z + W[3]*win[3].z +
            W[4]*win[4].z + W[5]*win[5].z + W[6]*nw[i].z;
      v.w = W[0]*win[0].w + W[1]*win[1].w + W[2]*win[2].w + W[3]*win[3].w +
            W[4]*win[4].w + W[5]*win[5].w + W[6]*nw[i].w;
#pragma unroll
      for (int j = 0; j < 5; ++j) win[j] = win[j + 1];
      win[5] = nw[i];

      float* lrow = &lds[i][HALO];
      *reinterpret_cast<float4*>(lrow + 4 * t) = v;   // contiguous b128 write

      // reflect-101 halo scatter (thread t owns floats 4t..4t+3 of the row)
      if (t == 0) {                  // floats 0..3
        lrow[-3] = v.w;              // f3 -> h-3
      } else if (t == 1) {           // floats 4..7
        lrow[-2] = v.x; lrow[-1] = v.y; lrow[-6] = v.z; lrow[-5] = v.w;
      } else if (t == 2) {           // floats 8..11
        lrow[-4] = v.x; lrow[-9] = v.y; lrow[-8] = v.z; lrow[-7] = v.w;
      } else if (t == NT - 3) {      // floats 1524..1527
        lrow[1542] = v.x; lrow[1543] = v.y; lrow[1544] = v.z; lrow[1539] = v.w;
      } else if (t == NT - 2) {      // floats 1528..1531
        lrow[1540] = v.x; lrow[1541] = v.y; lrow[1536] = v.z; lrow[1537] = v.w;
      } else if (t == NT - 1) {      // floats 1532..1535
        lrow[1538] = v.x;
      }
    }
    __syncthreads();

    // ---- horizontal pass: 8 rows x 192 groups = 1536 tasks / 384 threads ----
    const int r2 = (t >= NGRP) ? 1 : 0;
    const int g  = t - r2 * NGRP;                   // group 0..191 (8 floats each)
#pragma unroll
    for (int k = 0; k < NITER; ++k) {               // NITER==4 tasks per thread
      const int r = 2 * k + r2;                     // LDS row
      const float* rowp = &lds[r][HALO];
      float s[32];
#pragma unroll
      for (int j = 0; j < 8; ++j)                   // 8 aligned b128 reads
        *reinterpret_cast<float4*>(&s[4 * j]) =
            *reinterpret_cast<const float4*>(rowp + 8 * g - 12 + 4 * j);
      float o[8];
#pragma unroll
      for (int m = 0; m < 8; ++m)
        o[m] = W[0]*s[m+3]  + W[1]*s[m+6]  + W[2]*s[m+9]  + W[3]*s[m+12] +
               W[4]*s[m+15] + W[5]*s[m+18] + W[6]*s[m+21];
      float* orow = outN + (size_t)(hbase + r) * ROWF + 8 * g;
      *reinterpret_cast<float4*>(orow)     = make_float4(o[0], o[1], o[2], o[3]);
      *reinterpret_cast<float4*>(orow + 4) = make_float4(o[4], o[5], o[6], o[7]);
    }
    __syncthreads();
  }
}

}  // namespace

extern "C" void kernel_launch(void* const* d_in, const int* in_sizes, int n_in,
                              void* d_out, int out_size, void* d_ws, size_t ws_size,
                              hipStream_t stream) {
  const float* x = (const float*)d_in[0];
  float*       y = (float*)d_out;
  dim3 grid(64 * (HIMG / HCHUNK));   // 64 batches * 16 chunks = 1024 blocks
  dim3 block(NT);
  hipLaunchKernelGGL(gauss7, grid, block, 0, stream, x, y);
}

// Round 4
// 109.201 us; speedup vs baseline: 1.0875x; 1.0875x over previous
//
#include <hip/hip_runtime.h>

namespace {

constexpr int HIMG = 512;
constexpr int CH   = 3;
constexpr int ROWF = 512 * CH;          // 1536 floats per image row
constexpr int NT   = 384;               // one float4 column per thread
constexpr int RCH  = 4;                 // rows staged per iteration
constexpr int HCHUNK = 32;              // output rows per block
constexpr int NITER  = HCHUNK / RCH;    // 8
constexpr int HALO = 12;                // left halo floats (>=9, keeps b128 writes 16B-aligned)
constexpr int RP   = HALO + ROWF + HALO; // 1560 floats per LDS row

// exp(-x^2/(2*1.5^2)), double precision (matches cv2.getGaussianKernel)
constexpr double KD0 = 0.13533528323661270;  // x=3
constexpr double KD1 = 0.41111229050718745;  // x=2
constexpr double KD2 = 0.80073740291680804;  // x=1
constexpr double KSUM = 1.0 + 2.0 * (KD0 + KD1 + KD2);

__global__ __launch_bounds__(NT, 6) void gauss7(const float* __restrict__ in,
                                                float* __restrict__ out) {
  constexpr float W[7] = {
      (float)(KD0 / KSUM), (float)(KD1 / KSUM), (float)(KD2 / KSUM),
      (float)(1.0 / KSUM),
      (float)(KD2 / KSUM), (float)(KD1 / KSUM), (float)(KD0 / KSUM)};

  __shared__ __align__(16) float lds[RCH][RP];

  const int b  = blockIdx.x;
  const int n  = b >> 4;        // 16 H-chunks per image
  const int hc = b & 15;
  const int h0 = hc * HCHUNK;
  const int t  = threadIdx.x;

  const float* inN  = in  + (size_t)n * HIMG * ROWF;
  float*       outN = out + (size_t)n * HIMG * ROWF;
  const float4* inCol = reinterpret_cast<const float4*>(inN) + t;  // row stride = 384 float4

  // ---- vertical rolling window: win[0..5] = rows [h0-3 .. h0+2] ----
  float4 win[6];
#pragma unroll
  for (int i = 0; i < 6; ++i) {
    int r  = h0 - 3 + i;
    int rr = r < 0 ? -r : r;                  // top reflect-101 (preload only)
    win[i] = inCol[(size_t)rr * NT];
  }
  // ---- prefetched rows for the first iteration: rows h0+3 .. h0+6 ----
  float4 nw[RCH];
#pragma unroll
  for (int i = 0; i < RCH; ++i) nw[i] = inCol[(size_t)(h0 + 3 + i) * NT];  // <= 486, in range

  for (int it = 0; it < NITER; ++it) {
    const int hbase = h0 + it * RCH;

    // ---- vertical blur RCH rows -> LDS; re-issue each nw slot as next-iter prefetch ----
#pragma unroll
    for (int i = 0; i < RCH; ++i) {
      const float4 c = nw[i];
      float4 v;
      v.x = W[0]*win[0].x + W[1]*win[1].x + W[2]*win[2].x + W[3]*win[3].x +
            W[4]*win[4].x + W[5]*win[5].x + W[6]*c.x;
      v.y = W[0]*win[0].y + W[1]*win[1].y + W[2]*win[2].y + W[3]*win[3].y +
            W[4]*win[4].y + W[5]*win[5].y + W[6]*c.y;
      v.z = W[0]*win[0].z + W[1]*win[1].z + W[2]*win[2].z + W[3]*win[3].z +
            W[4]*win[4].z + W[5]*win[5].z + W[6]*c.z;
      v.w = W[0]*win[0].w + W[1]*win[1].w + W[2]*win[2].w + W[3]*win[3].w +
            W[4]*win[4].w + W[5]*win[5].w + W[6]*c.w;
#pragma unroll
      for (int j = 0; j < 5; ++j) win[j] = win[j + 1];
      win[5] = c;

      // prefetch the matching row of the NEXT iteration (latency hidden by
      // the rest of this iteration: FMAs + barrier + horizontal + barrier)
      {
        int r  = hbase + RCH + 3 + i;                       // 10..518
        int rr = r > HIMG - 1 ? 2 * (HIMG - 1) - r : r;
        nw[i]  = inCol[(size_t)rr * NT];
      }

      float* lrow = &lds[i][HALO];
      *reinterpret_cast<float4*>(lrow + 4 * t) = v;   // 16B-aligned, conflict-free

      // reflect-101 W-halo scatter — verified mapping from R2.
      // Thread t owns floats 4t..4t+3 (float f = 3*pix + ch).
      // Left:  halo pixel -p ch c (dest -3p+c) <- pixel p ch c (src 3p+c), p=1..3
      // Right: halo pixel 512+k ch c (dest 1536+3k+c) <- pixel 510-k ch c, k=0..2
      if (t == 0) {                  // floats 0..3
        lrow[-3] = v.w;              // f3  (p1,c0) -> -3
      } else if (t == 1) {           // floats 4..7
        lrow[-2] = v.x;              // f4  (p1,c1) -> -2
        lrow[-1] = v.y;              // f5  (p1,c2) -> -1
        lrow[-6] = v.z;              // f6  (p2,c0) -> -6
        lrow[-5] = v.w;              // f7  (p2,c1) -> -5
      } else if (t == 2) {           // floats 8..11
        lrow[-4] = v.x;              // f8  (p2,c2) -> -4
        lrow[-9] = v.y;              // f9  (p3,c0) -> -9
        lrow[-8] = v.z;              // f10 (p3,c1) -> -8
        lrow[-7] = v.w;              // f11 (p3,c2) -> -7
      } else if (t == NT - 3) {      // floats 1524..1527
        lrow[1542] = v.x;            // f1524 (p508,c0) -> halo p514,c0
        lrow[1543] = v.y;            // f1525 (p508,c1) -> halo p514,c1
        lrow[1544] = v.z;            // f1526 (p508,c2) -> halo p514,c2
        lrow[1539] = v.w;            // f1527 (p509,c0) -> halo p513,c0
      } else if (t == NT - 2) {      // floats 1528..1531
        lrow[1540] = v.x;            // f1528 (p509,c1) -> halo p513,c1
        lrow[1541] = v.y;            // f1529 (p509,c2) -> halo p513,c2
        lrow[1536] = v.z;            // f1530 (p510,c0) -> halo p512,c0
        lrow[1537] = v.w;            // f1531 (p510,c1) -> halo p512,c1
      } else if (t == NT - 1) {      // floats 1532..1535
        lrow[1538] = v.x;            // f1532 (p510,c2) -> halo p512,c2
      }
    }
    __syncthreads();

    // ---- horizontal pass: lane-stride-1 reads (2-way = conflict-free), taps +3 ----
#pragma unroll
    for (int k = 0; k < 16; ++k) {
      const int i = k >> 2;
      const int f = t + (k & 3) * NT;
      const float* p = &lds[i][HALO + f - 9];
      float o = W[0]*p[0]  + W[1]*p[3]  + W[2]*p[6]  + W[3]*p[9] +
                W[4]*p[12] + W[5]*p[15] + W[6]*p[18];
      outN[(size_t)(hbase + i) * ROWF + f] = o;
    }
    __syncthreads();
  }
}

}  // namespace

extern "C" void kernel_launch(void* const* d_in, const int* in_sizes, int n_in,
                              void* d_out, int out_size, void* d_ws, size_t ws_size,
                              hipStream_t stream) {
  const float* x = (const float*)d_in[0];
  float*       y = (float*)d_out;
  dim3 grid(64 * (HIMG / HCHUNK));   // 64 batches * 16 chunks = 1024 blocks (4/CU)
  dim3 block(NT);
  hipLaunchKernelGGL(gauss7, grid, block, 0, stream, x, y);
}

// Round 5
// 83.249 us; speedup vs baseline: 1.4265x; 1.3117x over previous
//
#include <hip/hip_runtime.h>

namespace {

constexpr int HIMG = 512;
constexpr int CH   = 3;
constexpr int ROWF = 512 * CH;           // 1536 floats per image row
constexpr int NT   = 384;                // one float4 column per thread
constexpr int RCH  = 4;                  // output rows per block
constexpr int NLOAD = RCH + 6;           // 10 input rows per block
constexpr int HALO = 12;                 // left halo floats (>=9, 16B aligned)
constexpr int RP   = HALO + ROWF + HALO; // 1560 floats per LDS row
constexpr int CHUNKS = HIMG / RCH;       // 128 chunks per image

// exp(-x^2/(2*1.5^2)), double precision (matches cv2.getGaussianKernel)
constexpr double KD0 = 0.13533528323661270;  // x=3
constexpr double KD1 = 0.41111229050718745;  // x=2
constexpr double KD2 = 0.80073740291680804;  // x=1
constexpr double KSUM = 1.0 + 2.0 * (KD0 + KD1 + KD2);

__global__ __launch_bounds__(NT, 6) void gauss7(const float* __restrict__ in,
                                                float* __restrict__ out) {
  constexpr float W[7] = {
      (float)(KD0 / KSUM), (float)(KD1 / KSUM), (float)(KD2 / KSUM),
      (float)(1.0 / KSUM),
      (float)(KD2 / KSUM), (float)(KD1 / KSUM), (float)(KD0 / KSUM)};

  __shared__ __align__(16) float lds[RCH][RP];

  // bijective XCD swizzle: 8192 blocks, 8 XCDs -> XCD k owns contiguous 1024
  // (neighboring chunks share 6 halo rows -> L2 hits within an XCD)
  const int bid = blockIdx.x;
  const int b   = (bid & 7) * (CHUNKS * 64 / 8) + (bid >> 3);

  const int n  = b >> 7;        // image index (128 chunks per image)
  const int hc = b & 127;
  const int h0 = hc * RCH;
  const int t  = threadIdx.x;

  const float* inN  = in  + (size_t)n * HIMG * ROWF;
  float*       outN = out + (size_t)n * HIMG * ROWF;
  const float4* inCol = reinterpret_cast<const float4*>(inN) + t;  // row stride = 384 float4

  // ---- issue ALL 10 row loads up front (reflect-101 in H) ----
  float4 rw[NLOAD];
#pragma unroll
  for (int i = 0; i < NLOAD; ++i) {
    int r  = h0 - 3 + i;
    int rr = r < 0 ? -r : (r > HIMG - 1 ? 2 * (HIMG - 1) - r : r);
    rw[i]  = inCol[(size_t)rr * NT];
  }

  // ---- vertical blur 4 rows -> LDS ----
#pragma unroll
  for (int i = 0; i < RCH; ++i) {
    float4 v;
    v.x = W[0]*rw[i].x + W[1]*rw[i+1].x + W[2]*rw[i+2].x + W[3]*rw[i+3].x +
          W[4]*rw[i+4].x + W[5]*rw[i+5].x + W[6]*rw[i+6].x;
    v.y = W[0]*rw[i].y + W[1]*rw[i+1].y + W[2]*rw[i+2].y + W[3]*rw[i+3].y +
          W[4]*rw[i+4].y + W[5]*rw[i+5].y + W[6]*rw[i+6].y;
    v.z = W[0]*rw[i].z + W[1]*rw[i+1].z + W[2]*rw[i+2].z + W[3]*rw[i+3].z +
          W[4]*rw[i+4].z + W[5]*rw[i+5].z + W[6]*rw[i+6].z;
    v.w = W[0]*rw[i].w + W[1]*rw[i+1].w + W[2]*rw[i+2].w + W[3]*rw[i+3].w +
          W[4]*rw[i+4].w + W[5]*rw[i+5].w + W[6]*rw[i+6].w;

    float* lrow = &lds[i][HALO];
    *reinterpret_cast<float4*>(lrow + 4 * t) = v;   // 16B-aligned, conflict-free

    // reflect-101 W-halo scatter (verified mapping, R2/R4)
    if (t == 0) {                  // floats 0..3
      lrow[-3] = v.w;              // f3  (p1,c0) -> -3
    } else if (t == 1) {           // floats 4..7
      lrow[-2] = v.x; lrow[-1] = v.y; lrow[-6] = v.z; lrow[-5] = v.w;
    } else if (t == 2) {           // floats 8..11
      lrow[-4] = v.x; lrow[-9] = v.y; lrow[-8] = v.z; lrow[-7] = v.w;
    } else if (t == NT - 3) {      // floats 1524..1527
      lrow[1542] = v.x; lrow[1543] = v.y; lrow[1544] = v.z; lrow[1539] = v.w;
    } else if (t == NT - 2) {      // floats 1528..1531
      lrow[1540] = v.x; lrow[1541] = v.y; lrow[1536] = v.z; lrow[1537] = v.w;
    } else if (t == NT - 1) {      // floats 1532..1535
      lrow[1538] = v.x;
    }
  }
  __syncthreads();

  // ---- horizontal pass: lane-stride-1 reads (conflict-free), taps +3 floats ----
#pragma unroll
  for (int k = 0; k < 4 * RCH; ++k) {
    const int i = k >> 2;                 // LDS row
    const int f = t + (k & 3) * NT;       // float column
    const float* p = &lds[i][HALO + f - 9];
    float o = W[0]*p[0]  + W[1]*p[3]  + W[2]*p[6]  + W[3]*p[9] +
              W[4]*p[12] + W[5]*p[15] + W[6]*p[18];
    outN[(size_t)(h0 + i) * ROWF + f] = o;
  }
}

}  // namespace

extern "C" void kernel_launch(void* const* d_in, const int* in_sizes, int n_in,
                              void* d_out, int out_size, void* d_ws, size_t ws_size,
                              hipStream_t stream) {
  const float* x = (const float*)d_in[0];
  float*       y = (float*)d_out;
  dim3 grid(64 * CHUNKS);   // 8192 blocks
  dim3 block(NT);
  hipLaunchKernelGGL(gauss7, grid, block, 0, stream, x, y);
}

// Round 6
// 63.188 us; speedup vs baseline: 1.8794x; 1.3175x over previous
//
#include <hip/hip_runtime.h>

namespace {

constexpr int HIMG = 512;
constexpr int CH   = 3;
constexpr int ROWF = 512 * CH;           // 1536 floats per image row
constexpr int NT   = 384;                // one float4 column per thread
constexpr int RCH  = 4;                  // output rows per block
constexpr int NLOAD = RCH + 6;           // 10 input rows per block
constexpr int HALO = 12;                 // halo floats each side (16B aligned)
constexpr int RP   = HALO + ROWF + HALO; // 1560 floats per LDS row
constexpr int CHUNKS = HIMG / RCH;       // 128 chunks per image

typedef float vf4 __attribute__((ext_vector_type(4)));

// exp(-x^2/(2*1.5^2)), double precision (matches cv2.getGaussianKernel)
constexpr double KD0 = 0.13533528323661270;  // x=3
constexpr double KD1 = 0.41111229050718745;  // x=2
constexpr double KD2 = 0.80073740291680804;  // x=1
constexpr double KSUM = 1.0 + 2.0 * (KD0 + KD1 + KD2);

__global__ __launch_bounds__(NT, 6) void gauss7(const float* __restrict__ in,
                                                float* __restrict__ out) {
  constexpr float W[7] = {
      (float)(KD0 / KSUM), (float)(KD1 / KSUM), (float)(KD2 / KSUM),
      (float)(1.0 / KSUM),
      (float)(KD2 / KSUM), (float)(KD1 / KSUM), (float)(KD0 / KSUM)};

  __shared__ __align__(16) float lds[RCH][RP];

  // bijective XCD swizzle: 8192 blocks, 8 XCDs -> XCD k owns contiguous 1024
  const int bid = blockIdx.x;
  const int b   = (bid & 7) * (CHUNKS * 64 / 8) + (bid >> 3);

  const int n  = b >> 7;        // image index (128 chunks per image)
  const int hc = b & 127;
  const int h0 = hc * RCH;
  const int t  = threadIdx.x;

  const float* inN  = in  + (size_t)n * HIMG * ROWF;
  float*       outN = out + (size_t)n * HIMG * ROWF;
  const float4* inCol = reinterpret_cast<const float4*>(inN) + t;  // row stride = 384 float4

  // ---- issue ALL 10 row loads up front (reflect-101 in H) ----
  float4 rw[NLOAD];
#pragma unroll
  for (int i = 0; i < NLOAD; ++i) {
    int r  = h0 - 3 + i;
    int rr = r < 0 ? -r : (r > HIMG - 1 ? 2 * (HIMG - 1) - r : r);
    rw[i]  = inCol[(size_t)rr * NT];
  }

  // ---- vertical blur 4 rows -> LDS ----
#pragma unroll
  for (int i = 0; i < RCH; ++i) {
    float4 v;
    v.x = W[0]*rw[i].x + W[1]*rw[i+1].x + W[2]*rw[i+2].x + W[3]*rw[i+3].x +
          W[4]*rw[i+4].x + W[5]*rw[i+5].x + W[6]*rw[i+6].x;
    v.y = W[0]*rw[i].y + W[1]*rw[i+1].y + W[2]*rw[i+2].y + W[3]*rw[i+3].y +
          W[4]*rw[i+4].y + W[5]*rw[i+5].y + W[6]*rw[i+6].y;
    v.z = W[0]*rw[i].z + W[1]*rw[i+1].z + W[2]*rw[i+2].z + W[3]*rw[i+3].z +
          W[4]*rw[i+4].z + W[5]*rw[i+5].z + W[6]*rw[i+6].z;
    v.w = W[0]*rw[i].w + W[1]*rw[i+1].w + W[2]*rw[i+2].w + W[3]*rw[i+3].w +
          W[4]*rw[i+4].w + W[5]*rw[i+5].w + W[6]*rw[i+6].w;

    float* lrow = &lds[i][HALO];
    *reinterpret_cast<float4*>(lrow + 4 * t) = v;   // 16B-aligned, conflict-free

    // reflect-101 W-halo scatter (verified mapping, R2/R4)
    if (t == 0) {                  // floats 0..3
      lrow[-3] = v.w;              // f3  (p1,c0) -> -3
    } else if (t == 1) {           // floats 4..7
      lrow[-2] = v.x; lrow[-1] = v.y; lrow[-6] = v.z; lrow[-5] = v.w;
    } else if (t == 2) {           // floats 8..11
      lrow[-4] = v.x; lrow[-9] = v.y; lrow[-8] = v.z; lrow[-7] = v.w;
    } else if (t == NT - 3) {      // floats 1524..1527
      lrow[1542] = v.x; lrow[1543] = v.y; lrow[1544] = v.z; lrow[1539] = v.w;
    } else if (t == NT - 2) {      // floats 1528..1531
      lrow[1540] = v.x; lrow[1541] = v.y; lrow[1536] = v.z; lrow[1537] = v.w;
    } else if (t == NT - 1) {      // floats 1532..1535
      lrow[1538] = v.x;
    }
  }
  __syncthreads();

  // ---- horizontal pass: thread t -> output floats 4t..4t+3 of each row ----
  // window: floats 4t-12 .. 4t+15 (28 floats, 7 x b128, 16B/lane contiguous)
#pragma unroll
  for (int k = 0; k < RCH; ++k) {
    const float* rowp = &lds[k][HALO + 4 * t - 12];
    float s[28];
#pragma unroll
    for (int j = 0; j < 7; ++j)
      *reinterpret_cast<float4*>(&s[4 * j]) =
          *reinterpret_cast<const float4*>(rowp + 4 * j);
    // out[4t+m] taps: s[m+3], s[m+6], ..., s[m+21]
    vf4 o;
#pragma unroll
    for (int m = 0; m < 4; ++m)
      o[m] = W[0]*s[m+3]  + W[1]*s[m+6]  + W[2]*s[m+9]  + W[3]*s[m+12] +
             W[4]*s[m+15] + W[5]*s[m+18] + W[6]*s[m+21];
    // non-temporal: output is never re-read; keep input resident in L2/L3
    vf4* orow = reinterpret_cast<vf4*>(outN + (size_t)(h0 + k) * ROWF);
    __builtin_nontemporal_store(o, orow + t);
  }
}

}  // namespace

extern "C" void kernel_launch(void* const* d_in, const int* in_sizes, int n_in,
                              void* d_out, int out_size, void* d_ws, size_t ws_size,
                              hipStream_t stream) {
  const float* x = (const float*)d_in[0];
  float*       y = (float*)d_out;
  dim3 grid(64 * CHUNKS);   // 8192 blocks
  dim3 block(NT);
  hipLaunchKernelGGL(gauss7, grid, block, 0, stream, x, y);
}